// Round 1
// baseline (213931.201 us; speedup 1.0000x reference)
//
#include <hip/hip_runtime.h>

#define RS 1024   // reservoir
#define SL 4096   // seq len
#define NB 1024   // batch
#define NI 16     // input size

typedef short s8v __attribute__((ext_vector_type(8)));
typedef float f16v __attribute__((ext_vector_type(16)));

static __device__ __forceinline__ unsigned short f2bf(float f) {
  unsigned u = __float_as_uint(f);
  u += 0x7fffu + ((u >> 16) & 1u);          // round-to-nearest-even
  return (unsigned short)(u >> 16);
}
static __device__ __forceinline__ float bf2f(unsigned short b) {
  return __uint_as_float(((unsigned)b) << 16);
}
static __device__ __forceinline__ float fast_tanh(float a) {
  float e = __expf(2.0f * a);               // saturates correctly at +/-inf
  return 1.0f - 2.0f / (e + 1.0f);
}

// prep: W fp32 -> bf16 (row-major), zero h0, zero barrier counters
__global__ __launch_bounds__(256) void prep_kernel(
    const float* __restrict__ W, unsigned short* __restrict__ wbf,
    unsigned int* __restrict__ h0u, int* __restrict__ cnt) {
  int idx = blockIdx.x * 256 + threadIdx.x;
  if (idx < RS * RS) wbf[idx] = f2bf(W[idx]);
  if (idx < (NB * RS) / 2) h0u[idx] = 0u;
  if (idx < 1024) cnt[idx] = 0;
}

// Persistent recurrent kernel.
// 256 WGs of 256 threads. Group g = bid>>4 owns batch rows [64g,64g+64).
// WG j = bid&15 owns reservoir cols [64j,64j+64); its W-slice lives in LDS
// (128 KB, XOR-swizzled to break the 2KB-row bank aliasing).
// One group barrier per step (monotonic counter, 16 arrivals per step).
__global__ __launch_bounds__(256) void esn_kernel(
    const float* __restrict__ x, const float* __restrict__ Win,
    unsigned short* __restrict__ ha, unsigned short* __restrict__ hb,
    const unsigned short* __restrict__ wbf, int* __restrict__ cnt) {
  extern __shared__ char smem[];
  const int bid = blockIdx.x;
  const int g = bid >> 4;
  const int j = bid & 15;
  const int tid = threadIdx.x;
  const int w = tid >> 6;
  const int lane = tid & 63;
  const int l31 = lane & 31;
  const int khalf = lane >> 5;

  // ---- stage swizzled W-slice (rows n = 64j .. 64j+63), once ----
  for (int idx = tid; idx < 64 * 128; idx += 256) {
    const int row = idx >> 7;          // 0..63
    const int chunk = idx & 127;       // 16B chunk in the 2KB row
    const int byteoff = (row << 11) | (chunk << 4);
    const int swz = byteoff ^ ((row & 15) << 4);
    const uint4 v = *(const uint4*)(wbf + (((j << 6) + row) << 10) + (chunk << 3));
    *(uint4*)(smem + swz) = v;
  }

  // wave (w>>1, w&1): rows [32*(w>>1),+32) of the 64-row m-slice,
  // cols [32*(w&1),+32) of the 64-col n-slice. 32x32x16 MFMA:
  // A lane: row=l31, k=8*khalf+i ; B lane: col=l31, k=8*khalf+i
  const int nloc = ((w & 1) << 5) | l31;           // col within slice
  const int nglb = (j << 6) | nloc;                // global reservoir col
  const int mrow = (g << 6) | ((w >> 1) << 5) | l31;  // global batch row (A frag)

  union U8 { s8v v; unsigned short u[8]; };
  U8 win_hi, win_lo;
  {
    const float* p = Win + nglb * NI + (khalf << 3);
#pragma unroll
    for (int i = 0; i < 8; i++) {
      float f = p[i];
      unsigned short hi = f2bf(f);
      win_hi.u[i] = hi;
      win_lo.u[i] = f2bf(f - bf2f(hi));
    }
  }
  __syncthreads();

  const int xorv = (nloc & 15) << 4;
  const int bbase = (nloc << 11) | (khalf << 4);
  int* mycnt = cnt + (g << 6);                     // 256B-spaced counters

  for (int t = 0; t < SL; t++) {
    const unsigned short* __restrict__ hcur = (t & 1) ? hb : ha;
    unsigned short* __restrict__ hnxt = (t & 1) ? ha : hb;

    // input projection fragments: x split hi/lo for ~fp32 accuracy
    U8 xhi, xlo;
    {
      const float* xp = x + ((size_t)mrow * SL + t) * NI + (khalf << 3);
#pragma unroll
      for (int i = 0; i < 8; i++) {
        float f = xp[i];
        unsigned short hi = f2bf(f);
        xhi.u[i] = hi;
        xlo.u[i] = f2bf(f - bf2f(hi));
      }
    }
    f16v acc = {};
    acc = __builtin_amdgcn_mfma_f32_32x32x16_bf16(xhi.v, win_hi.v, acc, 0, 0, 0);
    acc = __builtin_amdgcn_mfma_f32_32x32x16_bf16(xlo.v, win_hi.v, acc, 0, 0, 0);
    acc = __builtin_amdgcn_mfma_f32_32x32x16_bf16(xhi.v, win_lo.v, acc, 0, 0, 0);

    // main K loop: h[64 rows] @ W-slice^T, K=1024 in 64 steps of 16
    const unsigned short* arow = hcur + ((size_t)mrow << 10) + (khalf << 3);
#pragma unroll 8
    for (int kk = 0; kk < 64; kk++) {
      s8v av = *(const s8v*)(arow + (kk << 4));
      s8v bv = *(const s8v*)(smem + ((bbase + (kk << 5)) ^ xorv));
      acc = __builtin_amdgcn_mfma_f32_32x32x16_bf16(av, bv, acc, 0, 0, 0);
    }

    // epilogue: tanh + bf16 store. C/D: col=lane&31, row=(r&3)+8*(r>>2)+4*khalf
    union { f16v v; float f[16]; } a;
    a.v = acc;
    unsigned short* hn = hnxt + nglb;
    const int mbase = (g << 6) | ((w >> 1) << 5);
#pragma unroll
    for (int r = 0; r < 16; r++) {
      const int row = (r & 3) | ((r >> 2) << 3) | (khalf << 2);
      hn[(size_t)(mbase + row) << 10] = f2bf(fast_tanh(a.f[r]));
    }

    // group barrier (skip after last step; kernel boundary handles visibility)
    if (t != SL - 1) {
      __threadfence();
      __syncthreads();
      if (tid == 0) {
        __hip_atomic_fetch_add(mycnt, 1, __ATOMIC_RELEASE, __HIP_MEMORY_SCOPE_AGENT);
        const int target = (t + 1) << 4;
        while (__hip_atomic_load(mycnt, __ATOMIC_RELAXED, __HIP_MEMORY_SCOPE_AGENT) < target)
          __builtin_amdgcn_s_sleep(2);
        __threadfence();
      }
      __syncthreads();
    }
  }
}

// y = h_final @ Wout^T + b  (final h lives in buffer ha after 4096 steps)
__global__ __launch_bounds__(256) void yout_kernel(
    const unsigned short* __restrict__ h, const float* __restrict__ Wout,
    const float* __restrict__ bias, float* __restrict__ y) {
  const int tid = threadIdx.x;
  const int b = (blockIdx.x << 4) + (tid >> 4);
  const int o = tid & 15;
  const unsigned short* hr = h + ((size_t)b << 10);
  const float* wr = Wout + (o << 10);
  float s = 0.0f;
  for (int k = 0; k < RS; k += 8) {
#pragma unroll
    for (int i = 0; i < 8; i++) s += bf2f(hr[k + i]) * wr[k + i];
  }
  y[(b << 4) + o] = s + bias[o];
}

extern "C" void kernel_launch(void* const* d_in, const int* in_sizes, int n_in,
                              void* d_out, int out_size, void* d_ws, size_t ws_size,
                              hipStream_t stream) {
  const float* x = (const float*)d_in[0];
  const float* Win = (const float*)d_in[1];
  const float* W = (const float*)d_in[2];
  const float* Wout = (const float*)d_in[3];
  const float* bias = (const float*)d_in[4];
  float* y = (float*)d_out;

  char* ws = (char*)d_ws;
  unsigned short* h0 = (unsigned short*)ws;                 // 2 MB  (h buffer A; also final h)
  unsigned short* h1 = (unsigned short*)(ws + (1 << 21));   // 2 MB  (h buffer B)
  unsigned short* wbf = (unsigned short*)(ws + (2 << 21));  // 2 MB  (W bf16)
  int* cnt = (int*)(ws + 3 * (size_t)(1 << 21));            // 4 KB  (barrier counters)

  hipFuncSetAttribute((const void*)esn_kernel,
                      hipFuncAttributeMaxDynamicSharedMemorySize, 131072);

  prep_kernel<<<4096, 256, 0, stream>>>(W, wbf, (unsigned int*)h0, cnt);
  esn_kernel<<<256, 256, 131072, stream>>>(x, Win, h0, h1, wbf, cnt);
  yout_kernel<<<64, 256, 0, stream>>>(h0, Wout, bias, y);
}